// Round 11
// baseline (281.603 us; speedup 1.0000x reference)
//
#include <hip/hip_runtime.h>

// Head: out = dropout(Q K^T / 8, p=0.2) V  (no softmax). B=4 T=4096 E=1024 H=64.
// Round 11: block-specialized fusion. projmask kernel: blocks 0-511 = proj
// MFMA (VALU idle); blocks 512-2047 = packed threefry mask gen (pure VALU,
// 16 hashes -> 1 dword in attn consumption order). CU scheduler overlaps the
// two -> hash cost hides under proj memory/MFMA. attn-lean: 1 dword mask
// load + 3-op apply per element (R8 structure, no hash, (256,4)).

#define TB 4
#define TT 4096
#define TE 1024
#define TH 64
#define COMB_SCALE 0.15625f   // 0.125 * 1.25 folded into Q

#define NMASK (1024u * 4u * 16u * 64u)   // 4,194,304 dwords
#define MASKBLKS 1536

typedef __bf16 bf16x8 __attribute__((ext_vector_type(8)));
typedef __bf16 bf16x4 __attribute__((ext_vector_type(4)));
typedef float  f32x4  __attribute__((ext_vector_type(4)));

#define ROTL(x, d) __builtin_amdgcn_alignbit((x), (x), 32u - (d))

// Exact JAX threefry2x32, key (0,42); returns o0 ^ o1 (partitionable scheme).
__device__ __forceinline__ unsigned tf_bits(unsigned j) {
  const unsigned ks1 = 42u;
  const unsigned ks2 = 0x1BD11BDAu ^ 42u;
  unsigned x0 = 0u, x1 = j + ks1;
#define TF_RND(d) { x0 += x1; x1 = ROTL(x1, (d)); x1 ^= x0; }
  TF_RND(13u) TF_RND(15u) TF_RND(26u) TF_RND(6u)
  x0 += ks1; x1 += ks2 + 1u;
  TF_RND(17u) TF_RND(29u) TF_RND(16u) TF_RND(24u)
  x0 += ks2; x1 += 0u + 2u;
  TF_RND(13u) TF_RND(15u) TF_RND(26u) TF_RND(6u)
  x0 += 0u;  x1 += ks1 + 3u;
  TF_RND(17u) TF_RND(29u) TF_RND(16u) TF_RND(24u)
  x0 += ks1; x1 += ks2 + 4u;
  TF_RND(13u) TF_RND(15u) TF_RND(26u) TF_RND(6u)
  x0 += ks2; x1 += 0u + 5u;
#undef TF_RND
  return x0 ^ x1;
}

// keep <=> (bits>>9) < 6710887 (exact equiv of uniform<0.8f)
__device__ __forceinline__ unsigned tf_keep01(unsigned j) {
  return ((tf_bits(j) >> 9) < 6710887u) ? 1u : 0u;
}

// ---------------------------------------------------------------------------
// prep: WT bf16 [192][1024];  rows 0..63 <- Wq^T, 64..127 <- Wk^T, 128..191 <- Wv^T
// ---------------------------------------------------------------------------
__global__ __launch_bounds__(256)
void prep_wt(const float* __restrict__ Wq, const float* __restrict__ Wk,
             const float* __restrict__ Wv, __bf16* __restrict__ WT)
{
  __shared__ float lds[64][65];
  const int wi = blockIdx.x >> 4;          // 0=q 1=k 2=v
  const int k0 = (blockIdx.x & 15) * 64;
  const float* W = (wi == 0) ? Wq : ((wi == 1) ? Wk : Wv);
  const int tid = threadIdx.x;
#pragma unroll
  for (int it = 0; it < 16; ++it) {
    const int idx = tid + it * 256;
    lds[idx >> 6][idx & 63] = W[(size_t)(k0 + (idx >> 6)) * TH + (idx & 63)];
  }
  __syncthreads();
#pragma unroll
  for (int it = 0; it < 16; ++it) {
    const int idx = tid + it * 256;
    const int n = idx >> 6, kk = idx & 63;
    WT[(size_t)(wi * TH + n) * TE + k0 + kk] = (__bf16)lds[kk][n];
  }
}

// ---------------------------------------------------------------------------
// projmask: block-specialized.
//  blocks [0,512):    proj MFMA  (R9 body: 32 rows x 192 cols, x-prefetch)
//  blocks [512,2048): packed mask gen, grid-stride over 4.19M dwords.
// Mask dword d = ((A*4 + w)*16 + s)*64 + l, A=attn block (b*256+qt),
// w=KV quarter, s=k-step, l=lane; bit i=t*4+r -> element
// (row = qt*16 + (l>>4)*4 + r, col = w*1024 + s*64 + t*16 + (l&15)).
// ---------------------------------------------------------------------------
__global__ __launch_bounds__(256)
void projmask(const float* __restrict__ x, const __bf16* __restrict__ WT,
              __bf16* __restrict__ qs, __bf16* __restrict__ ks,
              __bf16* __restrict__ vT, unsigned* __restrict__ mask)
{
  const int tid = threadIdx.x;
  if (blockIdx.x >= 512) {
    // ---------------- mask generator ----------------
    const unsigned g0 = (unsigned)(blockIdx.x - 512) * 256u + (unsigned)tid;
    for (unsigned d = g0; d < NMASK; d += (unsigned)MASKBLKS * 256u) {
      const unsigned l  = d & 63u;
      const unsigned s  = (d >> 6) & 15u;
      const unsigned w  = (d >> 10) & 3u;
      const unsigned A  = d >> 12;
      const unsigned qt = A & 255u, bq = A >> 8;
      const unsigned row0 = (bq << 12) + qt * 16u + ((l >> 4) << 2);
      const unsigned col0 = (w << 10) + (s << 6) + (l & 15u);
      const unsigned jb = (row0 << 12) + col0;
      unsigned m = 0u;
#pragma unroll
      for (int t = 0; t < 4; ++t)
#pragma unroll
        for (int r = 0; r < 4; ++r)
          m |= tf_keep01(jb + (unsigned)((r << 12) + (t << 4))) << (t * 4 + r);
      mask[d] = m;
    }
    return;
  }

  // ---------------- projection ----------------
  const int w  = tid >> 6, l = tid & 63;
  const int l4 = l >> 4,  lm = l & 15;
  const int rh = w >> 1,  ch = w & 1;
  const int R  = blockIdx.x * 32 + rh * 16;

  const float*  xr = x  + (size_t)(R + lm) * TE;
  const __bf16* wt = WT + (size_t)(ch * 96 + lm) * TE;

  f32x4 acc[6];
#pragma unroll
  for (int t = 0; t < 6; ++t) acc[t] = (f32x4){0.f, 0.f, 0.f, 0.f};

  float4 u0 = *reinterpret_cast<const float4*>(xr + l4 * 8);
  float4 u1 = *reinterpret_cast<const float4*>(xr + l4 * 8 + 4);

  for (int k0 = 0; k0 < TE; k0 += 32) {
    const int kp = (k0 + 32 < TE) ? (k0 + 32) : 0;
    const float4 n0 = *reinterpret_cast<const float4*>(xr + kp + l4 * 8);
    const float4 n1 = *reinterpret_cast<const float4*>(xr + kp + l4 * 8 + 4);

    bf16x8 am;
    am[0] = (__bf16)u0.x; am[1] = (__bf16)u0.y;
    am[2] = (__bf16)u0.z; am[3] = (__bf16)u0.w;
    am[4] = (__bf16)u1.x; am[5] = (__bf16)u1.y;
    am[6] = (__bf16)u1.z; am[7] = (__bf16)u1.w;
    bf16x8 bn[6];
#pragma unroll
    for (int t = 0; t < 6; ++t)
      bn[t] = *reinterpret_cast<const bf16x8*>(wt + (size_t)t * 16 * TE + k0 + l4 * 8);
#pragma unroll
    for (int t = 0; t < 6; ++t)
      acc[t] = __builtin_amdgcn_mfma_f32_16x16x32_bf16(am, bn[t], acc[t], 0, 0, 0);

    u0 = n0; u1 = n1;
  }

  const int row0 = R + l4 * 4;
#pragma unroll
  for (int t = 0; t < 6; ++t) {
    const int n = ch * 96 + t * 16 + lm;
    if (n < TH) {
#pragma unroll
      for (int r = 0; r < 4; ++r)
        qs[(size_t)(row0 + r) * TH + n] = (__bf16)(acc[t][r] * COMB_SCALE);
    } else if (n < 2 * TH) {
#pragma unroll
      for (int r = 0; r < 4; ++r)
        ks[(size_t)(row0 + r) * TH + (n - TH)] = (__bf16)acc[t][r];
    } else {
      bf16x4 vv;
#pragma unroll
      for (int r = 0; r < 4; ++r) vv[r] = (__bf16)acc[t][r];
      const int bb = row0 >> 12, trow = row0 & (TT - 1);
      *reinterpret_cast<bf16x4*>(
          vT + ((size_t)(bb * TH + (n - 2 * TH)) * TT + trow)) = vv;
    }
  }
}

// ---------------------------------------------------------------------------
// Attention, lean MFMA. Grid 1024 x 256 thr: block -> (b, 16 q-rows);
// 4 waves = 4 KV quarters (16 k-steps of 64 keys). Mask: 1 dword load per
// wave-k-step; apply = bfe/sub/and. Barrier-free k-loop; 3-slot reduction.
// ---------------------------------------------------------------------------
__global__ __launch_bounds__(256, 4)
void attn_mfma(const __bf16* __restrict__ qs,
               const __bf16* __restrict__ ks,
               const __bf16* __restrict__ vT,
               const unsigned* __restrict__ mask,
               float* __restrict__ out)
{
  __shared__ __bf16 S_lds[4][16 * 64];   // wave-private, XOR-swizzled
  __shared__ float  Oex[3][16][TH + 4];  // KV-quarter exchange

  const int tid = threadIdx.x;
  const int w   = tid >> 6;   // 0..3
  const int l   = tid & 63;
  const int l4  = l >> 4;     // 0..3
  const int lm  = l & 15;     // 0..15

  const int b     = blockIdx.x >> 8;
  const int qt16  = blockIdx.x & 255;
  const int qrow0 = qt16 * 16;
  const int kv0   = w * (TT / 4);

  const __bf16* qb = qs + ((size_t)b * TT + qrow0) * TH;
  const bf16x8 qf0 = *reinterpret_cast<const bf16x8*>(qb + (size_t)lm * TH + l4 * 8);
  const bf16x8 qf1 = *reinterpret_cast<const bf16x8*>(qb + (size_t)lm * TH + 32 + l4 * 8);

  const __bf16* kbp = ks + (size_t)b * TT * TH;
  const __bf16* vbp = vT + (size_t)b * TH * TT;
  const unsigned* mkp = mask + (((size_t)blockIdx.x * 4 + w) * 16) * 64 + l;

  f32x4 o_acc[4];
#pragma unroll
  for (int t = 0; t < 4; ++t) o_acc[t] = (f32x4){0.f, 0.f, 0.f, 0.f};

  const unsigned sw = (unsigned)((lm & 7) << 3);

#pragma unroll 2
  for (int s = 0; s < 16; ++s) {
    const int kb = kv0 + s * 64;
    // ---- mask dword + K/V B-frag loads (issued up front) ----
    const unsigned m = mkp[s << 6];
    bf16x8 kf[4][2];
#pragma unroll
    for (int t = 0; t < 4; ++t) {
      const __bf16* kr = kbp + (size_t)(kb + t * 16 + lm) * TH;
#pragma unroll
      for (int ss = 0; ss < 2; ++ss)
        kf[t][ss] = *reinterpret_cast<const bf16x8*>(kr + ss * 32 + l4 * 8);
    }
    bf16x8 vf[4][2];
#pragma unroll
    for (int t = 0; t < 4; ++t) {
      const __bf16* vr = vbp + (size_t)(t * 16 + lm) * TT + kb;
#pragma unroll
      for (int ss = 0; ss < 2; ++ss)
        vf[t][ss] = *reinterpret_cast<const bf16x8*>(vr + ss * 32 + l4 * 8);
    }

    // ---- S = Q K^T (scale pre-folded into Q) ----
    f32x4 sa[4];
#pragma unroll
    for (int t = 0; t < 4; ++t) {
      f32x4 c = {0.f, 0.f, 0.f, 0.f};
      c = __builtin_amdgcn_mfma_f32_16x16x32_bf16(qf0, kf[t][0], c, 0, 0, 0);
      c = __builtin_amdgcn_mfma_f32_16x16x32_bf16(qf1, kf[t][1], c, 0, 0, 0);
      sa[t] = c;
    }

    // ---- apply mask bits + swizzled S store ----
#pragma unroll
    for (int t = 0; t < 4; ++t) {
#pragma unroll
      for (int r = 0; r < 4; ++r) {
        const unsigned keepneg = 0u - ((m >> (t * 4 + r)) & 1u);
        const unsigned sb = __float_as_uint(sa[t][r]) & keepneg;
        const int row = l4 * 4 + r;
        const int col = t * 16 + lm;
        S_lds[w][row * 64 + (col ^ ((row & 7) << 3))] =
            (__bf16)__uint_as_float(sb);
      }
    }

    // ---- reload S as PV A-frags ----
    const bf16x8 af0 = *reinterpret_cast<const bf16x8*>(
        &S_lds[w][lm * 64 + ((unsigned)(l4 * 8) ^ sw)]);
    const bf16x8 af1 = *reinterpret_cast<const bf16x8*>(
        &S_lds[w][lm * 64 + ((unsigned)(32 + l4 * 8) ^ sw)]);

    // ---- O += S V ----
#pragma unroll
    for (int t = 0; t < 4; ++t) {
      o_acc[t] = __builtin_amdgcn_mfma_f32_16x16x32_bf16(af0, vf[t][0], o_acc[t], 0, 0, 0);
      o_acc[t] = __builtin_amdgcn_mfma_f32_16x16x32_bf16(af1, vf[t][1], o_acc[t], 0, 0, 0);
    }
  }

  // ---- combine KV quarters ----
  if (w > 0) {
#pragma unroll
    for (int t = 0; t < 4; ++t)
#pragma unroll
      for (int r = 0; r < 4; ++r)
        Oex[w - 1][l4 * 4 + r][t * 16 + lm] = o_acc[t][r];
  }
  __syncthreads();
  if (w == 0) {
    float* outb = out + ((size_t)b * TT + qrow0) * TH;
#pragma unroll
    for (int t = 0; t < 4; ++t)
#pragma unroll
      for (int r = 0; r < 4; ++r) {
        const int row = l4 * 4 + r, col = t * 16 + lm;
        outb[(size_t)row * TH + col] = o_acc[t][r] + Oex[0][row][col] +
                                       Oex[1][row][col] + Oex[2][row][col];
      }
  }
}

extern "C" void kernel_launch(void* const* d_in, const int* in_sizes, int n_in,
                              void* d_out, int out_size, void* d_ws, size_t ws_size,
                              hipStream_t stream) {
  const float* x  = (const float*)d_in[0];
  const float* Wk = (const float*)d_in[1];
  const float* Wq = (const float*)d_in[2];
  const float* Wv = (const float*)d_in[3];
  float* outp = (float*)d_out;

  const size_t SZ = (size_t)TB * TT * TH;  // 1,048,576 elements each
  __bf16* q_ws  = (__bf16*)d_ws;
  __bf16* k_ws  = q_ws + SZ;
  __bf16* vT_ws = k_ws + SZ;
  __bf16* WT_ws = vT_ws + SZ;
  unsigned* mask_ws = (unsigned*)(WT_ws + 192 * TE);
  // ws use: 6 MB + 384 KB + 16.8 MB ~= 23.2 MB

  prep_wt<<<dim3(48), dim3(256), 0, stream>>>(Wq, Wk, Wv, WT_ws);
  projmask<<<dim3(512 + MASKBLKS), dim3(256), 0, stream>>>(
      x, WT_ws, q_ws, k_ws, vT_ws, mask_ws);
  attn_mfma<<<dim3(TB * (TT / 16)), dim3(256), 0, stream>>>(
      q_ws, k_ws, vT_ws, mask_ws, outp);
}

// Round 12
// 262.230 us; speedup vs baseline: 1.0739x; 1.0739x over previous
//
#include <hip/hip_runtime.h>

// Head: out = dropout(Q K^T / 8, p=0.2) V  (no softmax). B=4 T=4096 E=1024 H=64.
// Round 12: R8 structure (hash fused in attn = best, 203us) + two fixes:
// (1) proj: 1024 blocks (wave=16rx48c), x+WT 1-deep prefetch (was 2 waves/SIMD
//     with un-prefetched B loads -> 45us; floor ~15).
// (2) attn: explicit 2-deep K/V register pipeline (A/B named sets, full
//     unroll -> compile-time indices), loads hide under the hash stretch.
// Hash cost ledger: ~119us VALU machine-time wherever it runs (R8/R9/R11) —
// treat as empirical constant; only attn is long enough to hide it.

#define TB 4
#define TT 4096
#define TE 1024
#define TH 64
#define COMB_SCALE 0.15625f   // 0.125 * 1.25 folded into Q

typedef __bf16 bf16x8 __attribute__((ext_vector_type(8)));
typedef __bf16 bf16x4 __attribute__((ext_vector_type(4)));
typedef float  f32x4  __attribute__((ext_vector_type(4)));

#define ROTL(x, d) __builtin_amdgcn_alignbit((x), (x), 32u - (d))

// Exact JAX threefry2x32, key (0,42); returns o0 ^ o1 (partitionable scheme).
__device__ __forceinline__ unsigned tf_bits(unsigned j) {
  const unsigned ks1 = 42u;
  const unsigned ks2 = 0x1BD11BDAu ^ 42u;
  unsigned x0 = 0u, x1 = j + ks1;
#define TF_RND(d) { x0 += x1; x1 = ROTL(x1, (d)); x1 ^= x0; }
  TF_RND(13u) TF_RND(15u) TF_RND(26u) TF_RND(6u)
  x0 += ks1; x1 += ks2 + 1u;
  TF_RND(17u) TF_RND(29u) TF_RND(16u) TF_RND(24u)
  x0 += ks2; x1 += 0u + 2u;
  TF_RND(13u) TF_RND(15u) TF_RND(26u) TF_RND(6u)
  x0 += 0u;  x1 += ks1 + 3u;
  TF_RND(17u) TF_RND(29u) TF_RND(16u) TF_RND(24u)
  x0 += ks1; x1 += ks2 + 4u;
  TF_RND(13u) TF_RND(15u) TF_RND(26u) TF_RND(6u)
  x0 += ks2; x1 += 0u + 5u;
#undef TF_RND
  return x0 ^ x1;
}

// ---------------------------------------------------------------------------
// prep: WT bf16 [192][1024];  rows 0..63 <- Wq^T, 64..127 <- Wk^T, 128..191 <- Wv^T
// ---------------------------------------------------------------------------
__global__ __launch_bounds__(256)
void prep_wt(const float* __restrict__ Wq, const float* __restrict__ Wk,
             const float* __restrict__ Wv, __bf16* __restrict__ WT)
{
  __shared__ float lds[64][65];
  const int wi = blockIdx.x >> 4;          // 0=q 1=k 2=v
  const int k0 = (blockIdx.x & 15) * 64;
  const float* W = (wi == 0) ? Wq : ((wi == 1) ? Wk : Wv);
  const int tid = threadIdx.x;
#pragma unroll
  for (int it = 0; it < 16; ++it) {
    const int idx = tid + it * 256;
    lds[idx >> 6][idx & 63] = W[(size_t)(k0 + (idx >> 6)) * TH + (idx & 63)];
  }
  __syncthreads();
#pragma unroll
  for (int it = 0; it < 16; ++it) {
    const int idx = tid + it * 256;
    const int n = idx >> 6, kk = idx & 63;
    WT[(size_t)(wi * TH + n) * TE + k0 + kk] = (__bf16)lds[kk][n];
  }
}

// ---------------------------------------------------------------------------
// proj via MFMA: out[row][n] = sum_k x[row][k] * WT[n][k], n in [0,192).
// Grid 1024; block = 16 rows x 192 cols; wave w = 16 rows x cols [48w,48w+48).
// x and WT fragment loads 1-deep prefetched.
// ---------------------------------------------------------------------------
__global__ __launch_bounds__(256)
void proj_mfma(const float* __restrict__ x, const __bf16* __restrict__ WT,
               __bf16* __restrict__ qs, __bf16* __restrict__ ks,
               __bf16* __restrict__ vT)
{
  const int tid = threadIdx.x;
  const int w  = tid >> 6, l = tid & 63;
  const int l4 = l >> 4,  lm = l & 15;
  const int R  = blockIdx.x * 16;

  const float*  xr = x  + (size_t)(R + lm) * TE;
  const __bf16* wt = WT + (size_t)(w * 48 + lm) * TE;

  f32x4 acc[3];
#pragma unroll
  for (int t = 0; t < 3; ++t) acc[t] = (f32x4){0.f, 0.f, 0.f, 0.f};

  float4 u0 = *reinterpret_cast<const float4*>(xr + l4 * 8);
  float4 u1 = *reinterpret_cast<const float4*>(xr + l4 * 8 + 4);
  bf16x8 bnc[3];
#pragma unroll
  for (int t = 0; t < 3; ++t)
    bnc[t] = *reinterpret_cast<const bf16x8*>(wt + (size_t)t * 16 * TE + l4 * 8);

  for (int k0 = 0; k0 < TE; k0 += 32) {
    const int kp = (k0 + 32 < TE) ? (k0 + 32) : 0;
    const float4 n0 = *reinterpret_cast<const float4*>(xr + kp + l4 * 8);
    const float4 n1 = *reinterpret_cast<const float4*>(xr + kp + l4 * 8 + 4);
    bf16x8 bnn[3];
#pragma unroll
    for (int t = 0; t < 3; ++t)
      bnn[t] = *reinterpret_cast<const bf16x8*>(wt + (size_t)t * 16 * TE + kp + l4 * 8);

    bf16x8 am;
    am[0] = (__bf16)u0.x; am[1] = (__bf16)u0.y;
    am[2] = (__bf16)u0.z; am[3] = (__bf16)u0.w;
    am[4] = (__bf16)u1.x; am[5] = (__bf16)u1.y;
    am[6] = (__bf16)u1.z; am[7] = (__bf16)u1.w;
#pragma unroll
    for (int t = 0; t < 3; ++t)
      acc[t] = __builtin_amdgcn_mfma_f32_16x16x32_bf16(am, bnc[t], acc[t], 0, 0, 0);

    u0 = n0; u1 = n1;
#pragma unroll
    for (int t = 0; t < 3; ++t) bnc[t] = bnn[t];
  }

  const int row0 = R + l4 * 4;
#pragma unroll
  for (int t = 0; t < 3; ++t) {
    const int n = w * 48 + t * 16 + lm;
    if (n < TH) {
#pragma unroll
      for (int r = 0; r < 4; ++r)
        qs[(size_t)(row0 + r) * TH + n] = (__bf16)(acc[t][r] * COMB_SCALE);
    } else if (n < 2 * TH) {
#pragma unroll
      for (int r = 0; r < 4; ++r)
        ks[(size_t)(row0 + r) * TH + (n - TH)] = (__bf16)acc[t][r];
    } else {
      bf16x4 vv;
#pragma unroll
      for (int r = 0; r < 4; ++r) vv[r] = (__bf16)acc[t][r];
      const int bb = row0 >> 12, trow = row0 & (TT - 1);
      *reinterpret_cast<bf16x4*>(
          vT + ((size_t)(bb * TH + (n - 2 * TH)) * TT + trow)) = vv;
    }
  }
}

// ---------------------------------------------------------------------------
// Attention, MFMA + fused threefry, 2-deep K/V register pipeline.
// Grid 1024 x 256 thr: block -> (b, 16 q-rows); 4 waves = 4 KV quarters
// (16 k-steps of 64 keys). A/B named register sets, fully unrolled loop.
// ---------------------------------------------------------------------------
__global__ __launch_bounds__(256, 4)
void attn_mfma(const __bf16* __restrict__ qs,
               const __bf16* __restrict__ ks,
               const __bf16* __restrict__ vT,
               float* __restrict__ out)
{
  __shared__ __bf16 S_lds[4][16 * 64];   // wave-private, XOR-swizzled
  __shared__ float  Oex[3][16][TH + 4];  // KV-quarter exchange

  const int tid = threadIdx.x;
  const int w   = tid >> 6;   // 0..3
  const int l   = tid & 63;
  const int l4  = l >> 4;     // 0..3
  const int lm  = l & 15;     // 0..15

  const int b     = blockIdx.x >> 8;
  const int qt16  = blockIdx.x & 255;
  const int qrow0 = qt16 * 16;
  const int kv0   = w * (TT / 4);

  const __bf16* qb = qs + ((size_t)b * TT + qrow0) * TH;
  const bf16x8 qf0 = *reinterpret_cast<const bf16x8*>(qb + (size_t)lm * TH + l4 * 8);
  const bf16x8 qf1 = *reinterpret_cast<const bf16x8*>(qb + (size_t)lm * TH + 32 + l4 * 8);

  const __bf16* kbp = ks + (size_t)b * TT * TH;
  const __bf16* vbp = vT + (size_t)b * TH * TT;

  f32x4 o_acc[4];
#pragma unroll
  for (int t = 0; t < 4; ++t) o_acc[t] = (f32x4){0.f, 0.f, 0.f, 0.f};

  const unsigned base0 = ((unsigned)(b * TT) + (unsigned)qrow0 + (unsigned)(l4 * 4)) * (unsigned)TT;
  const unsigned sw = (unsigned)((lm & 7) << 3);

  bf16x8 kfA[4][2], vfA[4][2], kfB[4][2], vfB[4][2];

  auto loadkv = [&](bf16x8 (&kf)[4][2], bf16x8 (&vf)[4][2], int kb) {
#pragma unroll
    for (int t = 0; t < 4; ++t) {
      const __bf16* kr = kbp + (size_t)(kb + t * 16 + lm) * TH;
#pragma unroll
      for (int ss = 0; ss < 2; ++ss)
        kf[t][ss] = *reinterpret_cast<const bf16x8*>(kr + ss * 32 + l4 * 8);
    }
#pragma unroll
    for (int t = 0; t < 4; ++t) {
      const __bf16* vr = vbp + (size_t)(t * 16 + lm) * TT + kb;
#pragma unroll
      for (int ss = 0; ss < 2; ++ss)
        vf[t][ss] = *reinterpret_cast<const bf16x8*>(vr + ss * 32 + l4 * 8);
    }
  };

  auto work = [&](bf16x8 (&kf)[4][2], bf16x8 (&vf)[4][2], int kb) {
    // 16 threefry keep-masks (pure VALU; covers in-flight load latency)
    unsigned km[4][4];
    const unsigned j00 = base0 + (unsigned)kb + (unsigned)lm;
#pragma unroll
    for (int t = 0; t < 4; ++t)
#pragma unroll
      for (int r = 0; r < 4; ++r)
        km[t][r] = (tf_bits(j00 + (unsigned)((r << 12) + (t << 4))) <
                    3435974144u) ? 0xFFFFFFFFu : 0u;

    // S = Q K^T (scale pre-folded into Q)
    f32x4 sa[4];
#pragma unroll
    for (int t = 0; t < 4; ++t) {
      f32x4 c = {0.f, 0.f, 0.f, 0.f};
      c = __builtin_amdgcn_mfma_f32_16x16x32_bf16(qf0, kf[t][0], c, 0, 0, 0);
      c = __builtin_amdgcn_mfma_f32_16x16x32_bf16(qf1, kf[t][1], c, 0, 0, 0);
      sa[t] = c;
    }

    // apply mask (branchless int AND) + swizzled S store
#pragma unroll
    for (int t = 0; t < 4; ++t) {
#pragma unroll
      for (int r = 0; r < 4; ++r) {
        const unsigned sb = __float_as_uint(sa[t][r]) & km[t][r];
        const int row = l4 * 4 + r;
        const int col = t * 16 + lm;
        S_lds[w][row * 64 + (col ^ ((row & 7) << 3))] =
            (__bf16)__uint_as_float(sb);
      }
    }

    // reload S as PV A-frags (same-wave LDS FIFO ordering)
    const bf16x8 af0 = *reinterpret_cast<const bf16x8*>(
        &S_lds[w][lm * 64 + ((unsigned)(l4 * 8) ^ sw)]);
    const bf16x8 af1 = *reinterpret_cast<const bf16x8*>(
        &S_lds[w][lm * 64 + ((unsigned)(32 + l4 * 8) ^ sw)]);

    // O += S V
#pragma unroll
    for (int t = 0; t < 4; ++t) {
      o_acc[t] = __builtin_amdgcn_mfma_f32_16x16x32_bf16(af0, vf[t][0], o_acc[t], 0, 0, 0);
      o_acc[t] = __builtin_amdgcn_mfma_f32_16x16x32_bf16(af1, vf[t][1], o_acc[t], 0, 0, 0);
    }
  };

  loadkv(kfA, vfA, kv0);
#pragma unroll
  for (int s = 0; s < 16; s += 2) {
    loadkv(kfB, vfB, kv0 + (s + 1) * 64);
    work(kfA, vfA, kv0 + s * 64);
    if (s + 2 < 16) loadkv(kfA, vfA, kv0 + (s + 2) * 64);
    work(kfB, vfB, kv0 + (s + 1) * 64);
  }

  // ---- combine KV quarters ----
  if (w > 0) {
#pragma unroll
    for (int t = 0; t < 4; ++t)
#pragma unroll
      for (int r = 0; r < 4; ++r)
        Oex[w - 1][l4 * 4 + r][t * 16 + lm] = o_acc[t][r];
  }
  __syncthreads();
  if (w == 0) {
    float* outb = out + ((size_t)b * TT + qrow0) * TH;
#pragma unroll
    for (int t = 0; t < 4; ++t)
#pragma unroll
      for (int r = 0; r < 4; ++r) {
        const int row = l4 * 4 + r, col = t * 16 + lm;
        outb[(size_t)row * TH + col] = o_acc[t][r] + Oex[0][row][col] +
                                       Oex[1][row][col] + Oex[2][row][col];
      }
  }
}

extern "C" void kernel_launch(void* const* d_in, const int* in_sizes, int n_in,
                              void* d_out, int out_size, void* d_ws, size_t ws_size,
                              hipStream_t stream) {
  const float* x  = (const float*)d_in[0];
  const float* Wk = (const float*)d_in[1];
  const float* Wq = (const float*)d_in[2];
  const float* Wv = (const float*)d_in[3];
  float* outp = (float*)d_out;

  const size_t SZ = (size_t)TB * TT * TH;  // 1,048,576 elements each
  __bf16* q_ws  = (__bf16*)d_ws;
  __bf16* k_ws  = q_ws + SZ;
  __bf16* vT_ws = k_ws + SZ;
  __bf16* WT_ws = vT_ws + SZ;
  // ws use: 6 MB + 384 KB

  prep_wt<<<dim3(48), dim3(256), 0, stream>>>(Wq, Wk, Wv, WT_ws);
  proj_mfma<<<dim3(TB * TT / 16), dim3(256), 0, stream>>>(
      x, WT_ws, q_ws, k_ws, vT_ws);
  attn_mfma<<<dim3(TB * (TT / 16)), dim3(256), 0, stream>>>(
      q_ws, k_ws, vT_ws, outp);
}

// Round 13
// 212.301 us; speedup vs baseline: 1.3264x; 1.2352x over previous
//
#include <hip/hip_runtime.h>

// Head: out = dropout(Q K^T / 8, p=0.2) V  (no softmax). B=4 T=4096 E=1024 H=64.
// Round 13: recovery to R8's proven attn (best: 154us attn / 203 total;
// R12's A/B pipeline spilled to scratch: WRITE_SIZE 298MB). Deltas vs R8:
// (1) s_setprio(1) around MFMA clusters (T5: +4-7% on barrier-free attn
//     waves -- our regime), (2) proj = R12's 1024-block prefetched version
//     (4 waves/SIMD for its latency-bound loop).
// Ledger: hash ~120us machine-VALU wherever it runs; attn VALU-issue-bound.

#define TB 4
#define TT 4096
#define TE 1024
#define TH 64
#define COMB_SCALE 0.15625f   // 0.125 * 1.25 folded into Q

typedef __bf16 bf16x8 __attribute__((ext_vector_type(8)));
typedef __bf16 bf16x4 __attribute__((ext_vector_type(4)));
typedef float  f32x4  __attribute__((ext_vector_type(4)));

#define ROTL(x, d) __builtin_amdgcn_alignbit((x), (x), 32u - (d))

// Exact JAX threefry2x32, key (0,42); returns o0 ^ o1 (partitionable scheme).
__device__ __forceinline__ unsigned tf_bits(unsigned j) {
  const unsigned ks1 = 42u;
  const unsigned ks2 = 0x1BD11BDAu ^ 42u;
  unsigned x0 = 0u, x1 = j + ks1;
#define TF_RND(d) { x0 += x1; x1 = ROTL(x1, (d)); x1 ^= x0; }
  TF_RND(13u) TF_RND(15u) TF_RND(26u) TF_RND(6u)
  x0 += ks1; x1 += ks2 + 1u;
  TF_RND(17u) TF_RND(29u) TF_RND(16u) TF_RND(24u)
  x0 += ks2; x1 += 0u + 2u;
  TF_RND(13u) TF_RND(15u) TF_RND(26u) TF_RND(6u)
  x0 += 0u;  x1 += ks1 + 3u;
  TF_RND(17u) TF_RND(29u) TF_RND(16u) TF_RND(24u)
  x0 += ks1; x1 += ks2 + 4u;
  TF_RND(13u) TF_RND(15u) TF_RND(26u) TF_RND(6u)
  x0 += ks2; x1 += 0u + 5u;
#undef TF_RND
  return x0 ^ x1;
}

// keep <=> uniform(bits) < 0.8f <=> bits < 6710887<<9 (exact); all-ones/zero.
__device__ __forceinline__ unsigned tf_keepmask(unsigned j) {
  return tf_bits(j) < 3435974144u ? 0xFFFFFFFFu : 0u;
}

// ---------------------------------------------------------------------------
// prep: WT bf16 [192][1024];  rows 0..63 <- Wq^T, 64..127 <- Wk^T, 128..191 <- Wv^T
// ---------------------------------------------------------------------------
__global__ __launch_bounds__(256)
void prep_wt(const float* __restrict__ Wq, const float* __restrict__ Wk,
             const float* __restrict__ Wv, __bf16* __restrict__ WT)
{
  __shared__ float lds[64][65];
  const int wi = blockIdx.x >> 4;          // 0=q 1=k 2=v
  const int k0 = (blockIdx.x & 15) * 64;
  const float* W = (wi == 0) ? Wq : ((wi == 1) ? Wk : Wv);
  const int tid = threadIdx.x;
#pragma unroll
  for (int it = 0; it < 16; ++it) {
    const int idx = tid + it * 256;
    lds[idx >> 6][idx & 63] = W[(size_t)(k0 + (idx >> 6)) * TH + (idx & 63)];
  }
  __syncthreads();
#pragma unroll
  for (int it = 0; it < 16; ++it) {
    const int idx = tid + it * 256;
    const int n = idx >> 6, kk = idx & 63;
    WT[(size_t)(wi * TH + n) * TE + k0 + kk] = (__bf16)lds[kk][n];
  }
}

// ---------------------------------------------------------------------------
// proj via MFMA: out[row][n] = sum_k x[row][k] * WT[n][k], n in [0,192).
// Grid 1024; block = 16 rows x 192 cols; wave w = 16 rows x cols [48w,48w+48).
// x and WT fragment loads 1-deep prefetched.
// ---------------------------------------------------------------------------
__global__ __launch_bounds__(256)
void proj_mfma(const float* __restrict__ x, const __bf16* __restrict__ WT,
               __bf16* __restrict__ qs, __bf16* __restrict__ ks,
               __bf16* __restrict__ vT)
{
  const int tid = threadIdx.x;
  const int w  = tid >> 6, l = tid & 63;
  const int l4 = l >> 4,  lm = l & 15;
  const int R  = blockIdx.x * 16;

  const float*  xr = x  + (size_t)(R + lm) * TE;
  const __bf16* wt = WT + (size_t)(w * 48 + lm) * TE;

  f32x4 acc[3];
#pragma unroll
  for (int t = 0; t < 3; ++t) acc[t] = (f32x4){0.f, 0.f, 0.f, 0.f};

  float4 u0 = *reinterpret_cast<const float4*>(xr + l4 * 8);
  float4 u1 = *reinterpret_cast<const float4*>(xr + l4 * 8 + 4);
  bf16x8 bnc[3];
#pragma unroll
  for (int t = 0; t < 3; ++t)
    bnc[t] = *reinterpret_cast<const bf16x8*>(wt + (size_t)t * 16 * TE + l4 * 8);

  for (int k0 = 0; k0 < TE; k0 += 32) {
    const int kp = (k0 + 32 < TE) ? (k0 + 32) : 0;
    const float4 n0 = *reinterpret_cast<const float4*>(xr + kp + l4 * 8);
    const float4 n1 = *reinterpret_cast<const float4*>(xr + kp + l4 * 8 + 4);
    bf16x8 bnn[3];
#pragma unroll
    for (int t = 0; t < 3; ++t)
      bnn[t] = *reinterpret_cast<const bf16x8*>(wt + (size_t)t * 16 * TE + kp + l4 * 8);

    bf16x8 am;
    am[0] = (__bf16)u0.x; am[1] = (__bf16)u0.y;
    am[2] = (__bf16)u0.z; am[3] = (__bf16)u0.w;
    am[4] = (__bf16)u1.x; am[5] = (__bf16)u1.y;
    am[6] = (__bf16)u1.z; am[7] = (__bf16)u1.w;
#pragma unroll
    for (int t = 0; t < 3; ++t)
      acc[t] = __builtin_amdgcn_mfma_f32_16x16x32_bf16(am, bnc[t], acc[t], 0, 0, 0);

    u0 = n0; u1 = n1;
#pragma unroll
    for (int t = 0; t < 3; ++t) bnc[t] = bnn[t];
  }

  const int row0 = R + l4 * 4;
#pragma unroll
  for (int t = 0; t < 3; ++t) {
    const int n = w * 48 + t * 16 + lm;
    if (n < TH) {
#pragma unroll
      for (int r = 0; r < 4; ++r)
        qs[(size_t)(row0 + r) * TH + n] = (__bf16)(acc[t][r] * COMB_SCALE);
    } else if (n < 2 * TH) {
#pragma unroll
      for (int r = 0; r < 4; ++r)
        ks[(size_t)(row0 + r) * TH + (n - TH)] = (__bf16)acc[t][r];
    } else {
      bf16x4 vv;
#pragma unroll
      for (int r = 0; r < 4; ++r) vv[r] = (__bf16)acc[t][r];
      const int bb = row0 >> 12, trow = row0 & (TT - 1);
      *reinterpret_cast<bf16x4*>(
          vT + ((size_t)(bb * TH + (n - 2 * TH)) * TT + trow)) = vv;
    }
  }
}

// ---------------------------------------------------------------------------
// Attention, MFMA + fused threefry (R8 body + s_setprio around MFMA).
// Grid 1024 x 256 thr: block -> (b, 16 q-rows); 4 waves = 4 KV quarters
// (16 k-steps of 64 keys each). Barrier-free k-loop; 3-slot reduction.
// ---------------------------------------------------------------------------
__global__ __launch_bounds__(256, 4)
void attn_mfma(const __bf16* __restrict__ qs,
               const __bf16* __restrict__ ks,
               const __bf16* __restrict__ vT,
               float* __restrict__ out)
{
  __shared__ __bf16 S_lds[4][16 * 64];   // wave-private, XOR-swizzled
  __shared__ float  Oex[3][16][TH + 4];  // KV-quarter exchange

  const int tid = threadIdx.x;
  const int w   = tid >> 6;   // 0..3
  const int l   = tid & 63;
  const int l4  = l >> 4;     // 0..3
  const int lm  = l & 15;     // 0..15

  const int b     = blockIdx.x >> 8;
  const int qt16  = blockIdx.x & 255;
  const int qrow0 = qt16 * 16;
  const int kv0   = w * (TT / 4);

  const __bf16* qb = qs + ((size_t)b * TT + qrow0) * TH;
  const bf16x8 qf0 = *reinterpret_cast<const bf16x8*>(qb + (size_t)lm * TH + l4 * 8);
  const bf16x8 qf1 = *reinterpret_cast<const bf16x8*>(qb + (size_t)lm * TH + 32 + l4 * 8);

  const __bf16* kbp = ks + (size_t)b * TT * TH;
  const __bf16* vbp = vT + (size_t)b * TH * TT;

  f32x4 o_acc[4];
#pragma unroll
  for (int t = 0; t < 4; ++t) o_acc[t] = (f32x4){0.f, 0.f, 0.f, 0.f};

  const unsigned base0 = ((unsigned)(b * TT) + (unsigned)qrow0 + (unsigned)(l4 * 4)) * (unsigned)TT;
  const unsigned sw = (unsigned)((lm & 7) << 3);

  for (int kb = kv0; kb < kv0 + TT / 4; kb += 64) {
    // ---- issue K and V B-frag loads first (latency hides under hashes) ----
    bf16x8 kf[4][2];
#pragma unroll
    for (int t = 0; t < 4; ++t) {
      const __bf16* kr = kbp + (size_t)(kb + t * 16 + lm) * TH;
#pragma unroll
      for (int ss = 0; ss < 2; ++ss)
        kf[t][ss] = *reinterpret_cast<const bf16x8*>(kr + ss * 32 + l4 * 8);
    }
    bf16x8 vf[4][2];
#pragma unroll
    for (int t = 0; t < 4; ++t) {
      const __bf16* vr = vbp + (size_t)(t * 16 + lm) * TT + kb;
#pragma unroll
      for (int ss = 0; ss < 2; ++ss)
        vf[t][ss] = *reinterpret_cast<const bf16x8*>(vr + ss * 32 + l4 * 8);
    }

    // ---- 16 threefry keep-masks (pure VALU, hides load latency) ----
    unsigned km[4][4];
    const unsigned jcol = (unsigned)kb + (unsigned)lm;
#pragma unroll
    for (int t = 0; t < 4; ++t)
#pragma unroll
      for (int r = 0; r < 4; ++r)
        km[t][r] = tf_keepmask(base0 + (unsigned)(r << 12) + jcol + (unsigned)(t << 4));

    // ---- S = Q K^T (scale pre-folded into Q) ----
    __builtin_amdgcn_s_setprio(1);
    f32x4 sa[4];
#pragma unroll
    for (int t = 0; t < 4; ++t) {
      f32x4 c = {0.f, 0.f, 0.f, 0.f};
      c = __builtin_amdgcn_mfma_f32_16x16x32_bf16(qf0, kf[t][0], c, 0, 0, 0);
      c = __builtin_amdgcn_mfma_f32_16x16x32_bf16(qf1, kf[t][1], c, 0, 0, 0);
      sa[t] = c;
    }
    __builtin_amdgcn_s_setprio(0);

    // ---- apply mask bits (branchless int AND) + swizzled S store ----
#pragma unroll
    for (int t = 0; t < 4; ++t) {
#pragma unroll
      for (int r = 0; r < 4; ++r) {
        const unsigned sb = __float_as_uint(sa[t][r]) & km[t][r];
        const int row = l4 * 4 + r;
        const int col = t * 16 + lm;
        S_lds[w][row * 64 + (col ^ ((row & 7) << 3))] =
            (__bf16)__uint_as_float(sb);
      }
    }

    // ---- reload S as PV A-frags (same-wave dep; compiler inserts lgkmcnt) ----
    const bf16x8 af0 = *reinterpret_cast<const bf16x8*>(
        &S_lds[w][lm * 64 + ((unsigned)(l4 * 8) ^ sw)]);
    const bf16x8 af1 = *reinterpret_cast<const bf16x8*>(
        &S_lds[w][lm * 64 + ((unsigned)(32 + l4 * 8) ^ sw)]);

    // ---- O += S V ----
    __builtin_amdgcn_s_setprio(1);
#pragma unroll
    for (int t = 0; t < 4; ++t) {
      o_acc[t] = __builtin_amdgcn_mfma_f32_16x16x32_bf16(af0, vf[t][0], o_acc[t], 0, 0, 0);
      o_acc[t] = __builtin_amdgcn_mfma_f32_16x16x32_bf16(af1, vf[t][1], o_acc[t], 0, 0, 0);
    }
    __builtin_amdgcn_s_setprio(0);
  }

  // ---- combine KV quarters ----
  if (w > 0) {
#pragma unroll
    for (int t = 0; t < 4; ++t)
#pragma unroll
      for (int r = 0; r < 4; ++r)
        Oex[w - 1][l4 * 4 + r][t * 16 + lm] = o_acc[t][r];
  }
  __syncthreads();
  if (w == 0) {
    float* outb = out + ((size_t)b * TT + qrow0) * TH;
#pragma unroll
    for (int t = 0; t < 4; ++t)
#pragma unroll
      for (int r = 0; r < 4; ++r) {
        const int row = l4 * 4 + r, col = t * 16 + lm;
        outb[(size_t)row * TH + col] = o_acc[t][r] + Oex[0][row][col] +
                                       Oex[1][row][col] + Oex[2][row][col];
      }
  }
}

extern "C" void kernel_launch(void* const* d_in, const int* in_sizes, int n_in,
                              void* d_out, int out_size, void* d_ws, size_t ws_size,
                              hipStream_t stream) {
  const float* x  = (const float*)d_in[0];
  const float* Wk = (const float*)d_in[1];
  const float* Wq = (const float*)d_in[2];
  const float* Wv = (const float*)d_in[3];
  float* outp = (float*)d_out;

  const size_t SZ = (size_t)TB * TT * TH;  // 1,048,576 elements each
  __bf16* q_ws  = (__bf16*)d_ws;
  __bf16* k_ws  = q_ws + SZ;
  __bf16* vT_ws = k_ws + SZ;
  __bf16* WT_ws = vT_ws + SZ;
  // ws use: 6 MB + 384 KB

  prep_wt<<<dim3(48), dim3(256), 0, stream>>>(Wq, Wk, Wv, WT_ws);
  proj_mfma<<<dim3(TB * TT / 16), dim3(256), 0, stream>>>(
      x, WT_ws, q_ws, k_ws, vT_ws);
  attn_mfma<<<dim3(TB * (TT / 16)), dim3(256), 0, stream>>>(
      q_ws, k_ws, vT_ws, outp);
}

// Round 14
// 191.549 us; speedup vs baseline: 1.4701x; 1.1083x over previous
//
#include <hip/hip_runtime.h>

// Head: out = dropout(Q K^T / 8, p=0.2) V  (no softmax). B=4 T=4096 E=1024 H=64.
// Round 14: proj K-split. proj was per-wave serial-latency bound (~3375
// cy/iter vs ~230 issue). Block = 16 rows x 192 cols; 4 waves split K into
// 256-slices (8 iters each, 12 MFMA/iter), LDS 4-way reduction, same
// epilogue. attn = R13 verbatim (150us proven: R8 body + setprio).

#define TB 4
#define TT 4096
#define TE 1024
#define TH 64
#define COMB_SCALE 0.15625f   // 0.125 * 1.25 folded into Q

typedef __bf16 bf16x8 __attribute__((ext_vector_type(8)));
typedef __bf16 bf16x4 __attribute__((ext_vector_type(4)));
typedef float  f32x4  __attribute__((ext_vector_type(4)));

#define ROTL(x, d) __builtin_amdgcn_alignbit((x), (x), 32u - (d))

// Exact JAX threefry2x32, key (0,42); returns o0 ^ o1 (partitionable scheme).
__device__ __forceinline__ unsigned tf_bits(unsigned j) {
  const unsigned ks1 = 42u;
  const unsigned ks2 = 0x1BD11BDAu ^ 42u;
  unsigned x0 = 0u, x1 = j + ks1;
#define TF_RND(d) { x0 += x1; x1 = ROTL(x1, (d)); x1 ^= x0; }
  TF_RND(13u) TF_RND(15u) TF_RND(26u) TF_RND(6u)
  x0 += ks1; x1 += ks2 + 1u;
  TF_RND(17u) TF_RND(29u) TF_RND(16u) TF_RND(24u)
  x0 += ks2; x1 += 0u + 2u;
  TF_RND(13u) TF_RND(15u) TF_RND(26u) TF_RND(6u)
  x0 += 0u;  x1 += ks1 + 3u;
  TF_RND(17u) TF_RND(29u) TF_RND(16u) TF_RND(24u)
  x0 += ks1; x1 += ks2 + 4u;
  TF_RND(13u) TF_RND(15u) TF_RND(26u) TF_RND(6u)
  x0 += ks2; x1 += 0u + 5u;
#undef TF_RND
  return x0 ^ x1;
}

// keep <=> uniform(bits) < 0.8f <=> bits < 6710887<<9 (exact); all-ones/zero.
__device__ __forceinline__ unsigned tf_keepmask(unsigned j) {
  return tf_bits(j) < 3435974144u ? 0xFFFFFFFFu : 0u;
}

// ---------------------------------------------------------------------------
// prep: WT bf16 [192][1024];  rows 0..63 <- Wq^T, 64..127 <- Wk^T, 128..191 <- Wv^T
// ---------------------------------------------------------------------------
__global__ __launch_bounds__(256)
void prep_wt(const float* __restrict__ Wq, const float* __restrict__ Wk,
             const float* __restrict__ Wv, __bf16* __restrict__ WT)
{
  __shared__ float lds[64][65];
  const int wi = blockIdx.x >> 4;          // 0=q 1=k 2=v
  const int k0 = (blockIdx.x & 15) * 64;
  const float* W = (wi == 0) ? Wq : ((wi == 1) ? Wk : Wv);
  const int tid = threadIdx.x;
#pragma unroll
  for (int it = 0; it < 16; ++it) {
    const int idx = tid + it * 256;
    lds[idx >> 6][idx & 63] = W[(size_t)(k0 + (idx >> 6)) * TH + (idx & 63)];
  }
  __syncthreads();
#pragma unroll
  for (int it = 0; it < 16; ++it) {
    const int idx = tid + it * 256;
    const int n = idx >> 6, kk = idx & 63;
    WT[(size_t)(wi * TH + n) * TE + k0 + kk] = (__bf16)lds[kk][n];
  }
}

// ---------------------------------------------------------------------------
// proj via MFMA, K-split: block = 16 rows x 192 cols; wave w computes the
// FULL 16x192 tile for k in [256w, 256w+256) (8 iters, 12 MFMA each);
// 4-way LDS reduction; wave w stores cols [48w, 48w+48).
// ---------------------------------------------------------------------------
__global__ __launch_bounds__(256, 3)
void proj_mfma(const float* __restrict__ x, const __bf16* __restrict__ WT,
               __bf16* __restrict__ qs, __bf16* __restrict__ ks,
               __bf16* __restrict__ vT)
{
  __shared__ float red[4][16][196];
  const int tid = threadIdx.x;
  const int w  = tid >> 6, l = tid & 63;
  const int l4 = l >> 4,  lm = l & 15;
  const int R  = blockIdx.x * 16;

  const float*  xr = x  + (size_t)(R + lm) * TE + w * 256;
  const __bf16* wt = WT + (size_t)lm * TE + w * 256;

  f32x4 acc[12];
#pragma unroll
  for (int t = 0; t < 12; ++t) acc[t] = (f32x4){0.f, 0.f, 0.f, 0.f};

#pragma unroll
  for (int k0 = 0; k0 < 256; k0 += 32) {
    const float4 u0 = *reinterpret_cast<const float4*>(xr + k0 + l4 * 8);
    const float4 u1 = *reinterpret_cast<const float4*>(xr + k0 + l4 * 8 + 4);
    bf16x8 am;
    am[0] = (__bf16)u0.x; am[1] = (__bf16)u0.y;
    am[2] = (__bf16)u0.z; am[3] = (__bf16)u0.w;
    am[4] = (__bf16)u1.x; am[5] = (__bf16)u1.y;
    am[6] = (__bf16)u1.z; am[7] = (__bf16)u1.w;
    bf16x8 bn[12];
#pragma unroll
    for (int t = 0; t < 12; ++t)
      bn[t] = *reinterpret_cast<const bf16x8*>(wt + (size_t)t * 16 * TE + k0 + l4 * 8);
#pragma unroll
    for (int t = 0; t < 12; ++t)
      acc[t] = __builtin_amdgcn_mfma_f32_16x16x32_bf16(am, bn[t], acc[t], 0, 0, 0);
  }

  // publish partials
#pragma unroll
  for (int t = 0; t < 12; ++t)
#pragma unroll
    for (int r = 0; r < 4; ++r)
      red[w][l4 * 4 + r][t * 16 + lm] = acc[t][r];
  __syncthreads();

  // wave w: sum 4 partials for cols [48w, 48w+48) and store
  const int row0 = R + l4 * 4;
#pragma unroll
  for (int t2 = 0; t2 < 3; ++t2) {
    const int n = w * 48 + t2 * 16 + lm;
    float v[4];
#pragma unroll
    for (int r = 0; r < 4; ++r) {
      const int rr = l4 * 4 + r;
      v[r] = red[0][rr][n] + red[1][rr][n] + red[2][rr][n] + red[3][rr][n];
    }
    if (n < TH) {
#pragma unroll
      for (int r = 0; r < 4; ++r)
        qs[(size_t)(row0 + r) * TH + n] = (__bf16)(v[r] * COMB_SCALE);
    } else if (n < 2 * TH) {
#pragma unroll
      for (int r = 0; r < 4; ++r)
        ks[(size_t)(row0 + r) * TH + (n - TH)] = (__bf16)v[r];
    } else {
      bf16x4 vv;
#pragma unroll
      for (int r = 0; r < 4; ++r) vv[r] = (__bf16)v[r];
      const int bb = row0 >> 12, trow = row0 & (TT - 1);
      *reinterpret_cast<bf16x4*>(
          vT + ((size_t)(bb * TH + (n - 2 * TH)) * TT + trow)) = vv;
    }
  }
}

// ---------------------------------------------------------------------------
// Attention, MFMA + fused threefry (R13 verbatim: R8 body + s_setprio).
// Grid 1024 x 256 thr: block -> (b, 16 q-rows); 4 waves = 4 KV quarters
// (16 k-steps of 64 keys each). Barrier-free k-loop; 3-slot reduction.
// ---------------------------------------------------------------------------
__global__ __launch_bounds__(256, 4)
void attn_mfma(const __bf16* __restrict__ qs,
               const __bf16* __restrict__ ks,
               const __bf16* __restrict__ vT,
               float* __restrict__ out)
{
  __shared__ __bf16 S_lds[4][16 * 64];   // wave-private, XOR-swizzled
  __shared__ float  Oex[3][16][TH + 4];  // KV-quarter exchange

  const int tid = threadIdx.x;
  const int w   = tid >> 6;   // 0..3
  const int l   = tid & 63;
  const int l4  = l >> 4;     // 0..3
  const int lm  = l & 15;     // 0..15

  const int b     = blockIdx.x >> 8;
  const int qt16  = blockIdx.x & 255;
  const int qrow0 = qt16 * 16;
  const int kv0   = w * (TT / 4);

  const __bf16* qb = qs + ((size_t)b * TT + qrow0) * TH;
  const bf16x8 qf0 = *reinterpret_cast<const bf16x8*>(qb + (size_t)lm * TH + l4 * 8);
  const bf16x8 qf1 = *reinterpret_cast<const bf16x8*>(qb + (size_t)lm * TH + 32 + l4 * 8);

  const __bf16* kbp = ks + (size_t)b * TT * TH;
  const __bf16* vbp = vT + (size_t)b * TH * TT;

  f32x4 o_acc[4];
#pragma unroll
  for (int t = 0; t < 4; ++t) o_acc[t] = (f32x4){0.f, 0.f, 0.f, 0.f};

  const unsigned base0 = ((unsigned)(b * TT) + (unsigned)qrow0 + (unsigned)(l4 * 4)) * (unsigned)TT;
  const unsigned sw = (unsigned)((lm & 7) << 3);

  for (int kb = kv0; kb < kv0 + TT / 4; kb += 64) {
    // ---- issue K and V B-frag loads first (latency hides under hashes) ----
    bf16x8 kf[4][2];
#pragma unroll
    for (int t = 0; t < 4; ++t) {
      const __bf16* kr = kbp + (size_t)(kb + t * 16 + lm) * TH;
#pragma unroll
      for (int ss = 0; ss < 2; ++ss)
        kf[t][ss] = *reinterpret_cast<const bf16x8*>(kr + ss * 32 + l4 * 8);
    }
    bf16x8 vf[4][2];
#pragma unroll
    for (int t = 0; t < 4; ++t) {
      const __bf16* vr = vbp + (size_t)(t * 16 + lm) * TT + kb;
#pragma unroll
      for (int ss = 0; ss < 2; ++ss)
        vf[t][ss] = *reinterpret_cast<const bf16x8*>(vr + ss * 32 + l4 * 8);
    }

    // ---- 16 threefry keep-masks (pure VALU, hides load latency) ----
    unsigned km[4][4];
    const unsigned jcol = (unsigned)kb + (unsigned)lm;
#pragma unroll
    for (int t = 0; t < 4; ++t)
#pragma unroll
      for (int r = 0; r < 4; ++r)
        km[t][r] = tf_keepmask(base0 + (unsigned)(r << 12) + jcol + (unsigned)(t << 4));

    // ---- S = Q K^T (scale pre-folded into Q) ----
    __builtin_amdgcn_s_setprio(1);
    f32x4 sa[4];
#pragma unroll
    for (int t = 0; t < 4; ++t) {
      f32x4 c = {0.f, 0.f, 0.f, 0.f};
      c = __builtin_amdgcn_mfma_f32_16x16x32_bf16(qf0, kf[t][0], c, 0, 0, 0);
      c = __builtin_amdgcn_mfma_f32_16x16x32_bf16(qf1, kf[t][1], c, 0, 0, 0);
      sa[t] = c;
    }
    __builtin_amdgcn_s_setprio(0);

    // ---- apply mask bits (branchless int AND) + swizzled S store ----
#pragma unroll
    for (int t = 0; t < 4; ++t) {
#pragma unroll
      for (int r = 0; r < 4; ++r) {
        const unsigned sb = __float_as_uint(sa[t][r]) & km[t][r];
        const int row = l4 * 4 + r;
        const int col = t * 16 + lm;
        S_lds[w][row * 64 + (col ^ ((row & 7) << 3))] =
            (__bf16)__uint_as_float(sb);
      }
    }

    // ---- reload S as PV A-frags (same-wave dep; compiler inserts lgkmcnt) ----
    const bf16x8 af0 = *reinterpret_cast<const bf16x8*>(
        &S_lds[w][lm * 64 + ((unsigned)(l4 * 8) ^ sw)]);
    const bf16x8 af1 = *reinterpret_cast<const bf16x8*>(
        &S_lds[w][lm * 64 + ((unsigned)(32 + l4 * 8) ^ sw)]);

    // ---- O += S V ----
    __builtin_amdgcn_s_setprio(1);
#pragma unroll
    for (int t = 0; t < 4; ++t) {
      o_acc[t] = __builtin_amdgcn_mfma_f32_16x16x32_bf16(af0, vf[t][0], o_acc[t], 0, 0, 0);
      o_acc[t] = __builtin_amdgcn_mfma_f32_16x16x32_bf16(af1, vf[t][1], o_acc[t], 0, 0, 0);
    }
    __builtin_amdgcn_s_setprio(0);
  }

  // ---- combine KV quarters ----
  if (w > 0) {
#pragma unroll
    for (int t = 0; t < 4; ++t)
#pragma unroll
      for (int r = 0; r < 4; ++r)
        Oex[w - 1][l4 * 4 + r][t * 16 + lm] = o_acc[t][r];
  }
  __syncthreads();
  if (w == 0) {
    float* outb = out + ((size_t)b * TT + qrow0) * TH;
#pragma unroll
    for (int t = 0; t < 4; ++t)
#pragma unroll
      for (int r = 0; r < 4; ++r) {
        const int row = l4 * 4 + r, col = t * 16 + lm;
        outb[(size_t)row * TH + col] = o_acc[t][r] + Oex[0][row][col] +
                                       Oex[1][row][col] + Oex[2][row][col];
      }
  }
}

extern "C" void kernel_launch(void* const* d_in, const int* in_sizes, int n_in,
                              void* d_out, int out_size, void* d_ws, size_t ws_size,
                              hipStream_t stream) {
  const float* x  = (const float*)d_in[0];
  const float* Wk = (const float*)d_in[1];
  const float* Wq = (const float*)d_in[2];
  const float* Wv = (const float*)d_in[3];
  float* outp = (float*)d_out;

  const size_t SZ = (size_t)TB * TT * TH;  // 1,048,576 elements each
  __bf16* q_ws  = (__bf16*)d_ws;
  __bf16* k_ws  = q_ws + SZ;
  __bf16* vT_ws = k_ws + SZ;
  __bf16* WT_ws = vT_ws + SZ;
  // ws use: 6 MB + 384 KB

  prep_wt<<<dim3(48), dim3(256), 0, stream>>>(Wq, Wk, Wv, WT_ws);
  proj_mfma<<<dim3(TB * TT / 16), dim3(256), 0, stream>>>(
      x, WT_ws, q_ws, k_ws, vT_ws);
  attn_mfma<<<dim3(TB * (TT / 16)), dim3(256), 0, stream>>>(
      q_ws, k_ws, vT_ws, outp);
}